// Round 3
// baseline (563.626 us; speedup 1.0000x reference)
//
#include <hip/hip_runtime.h>
#include <math.h>
#include <float.h>

#define BB 8
#define FF 1024
#define NJ 17
#define CH 512
#define TOK 81
#define RCP_SQRT_C 0.04419417382415922f   // 1/sqrt(512)
#define LP 133                            // LDS row pad (stride%32=5, conflict-free col reads)

typedef short bf16x8 __attribute__((ext_vector_type(8)));   // 8 bf16 = 4 VGPRs
typedef float f32x16 __attribute__((ext_vector_type(16)));  // 32x32 MFMA acc

static __device__ inline unsigned short f2bf(float f) {
    __bf16 h = (__bf16)f;                       // RNE
    return __builtin_bit_cast(unsigned short, h);
}
static __device__ inline float bf2f(unsigned short u) {
    return (float)__builtin_bit_cast(__bf16, u);
}

// frag layout: [b][s(32)][h(2)][f(1024)][j(8)] bf16, uint4 index ((b*32+s)*2+h)*1024 + f

// ---------------- kernel 1: mean over joints + sumsq + hi/lo frag write -------
__global__ __launch_bounds__(256) void pool_kernel(const float* __restrict__ x,
                                                   uint4* __restrict__ fhi,
                                                   uint4* __restrict__ flo,
                                                   float* __restrict__ sq,
                                                   unsigned* __restrict__ ctrl) {
    const int t = threadIdx.x;
    if (blockIdx.x == 0 && t < 24) ctrl[t] = 0u;   // dmx[8] + sync counters, consumed 2 launches later
    const int wid = t >> 6, lane = t & 63;
    const int row0 = blockIdx.x * 4;            // 4 rows per block, one wave per row
    const int row = row0 + wid;
    const int b = row >> 10, f0 = row0 & 1023;
    const float* px = x + (size_t)row * NJ * CH + lane * 8;
    float a[8] = {};
    #pragma unroll
    for (int n = 0; n < NJ; ++n) {
        const float4 v0 = *(const float4*)(px + (size_t)n * CH);
        const float4 v1 = *(const float4*)(px + (size_t)n * CH + 4);
        a[0] += v0.x; a[1] += v0.y; a[2] += v0.z; a[3] += v0.w;
        a[4] += v1.x; a[5] += v1.y; a[6] += v1.z; a[7] += v1.w;
    }
    float ssq = 0.f;
    unsigned short hi[8], lo[8];
    #pragma unroll
    for (int j = 0; j < 8; ++j) {
        const float m = a[j] / 17.0f;
        ssq += m * m;
        hi[j] = f2bf(m);
        lo[j] = f2bf(m - bf2f(hi[j]));
    }
    #pragma unroll
    for (int off = 32; off > 0; off >>= 1) ssq += __shfl_down(ssq, off);
    if (lane == 0) sq[row] = ssq;

    uint4 uh, ul;
    uh.x = (unsigned)hi[0] | ((unsigned)hi[1] << 16);
    uh.y = (unsigned)hi[2] | ((unsigned)hi[3] << 16);
    uh.z = (unsigned)hi[4] | ((unsigned)hi[5] << 16);
    uh.w = (unsigned)hi[6] | ((unsigned)hi[7] << 16);
    ul.x = (unsigned)lo[0] | ((unsigned)lo[1] << 16);
    ul.y = (unsigned)lo[2] | ((unsigned)lo[3] << 16);
    ul.z = (unsigned)lo[4] | ((unsigned)lo[5] << 16);
    ul.w = (unsigned)lo[6] | ((unsigned)lo[7] << 16);
    __shared__ uint4 sh_hi[256], sh_lo[256];
    sh_hi[lane * 4 + wid] = uh;
    sh_lo[lane * 4 + wid] = ul;
    __syncthreads();
    const int k8 = t >> 2, fpr = t & 3;         // k8 chunk, frame-in-block
    const int s = k8 >> 1, h = k8 & 1;
    const size_t o = (((size_t)b * 32 + s) * 2 + h) * 1024 + f0 + fpr;
    fhi[o] = sh_hi[t];
    flo[o] = sh_lo[t];
}

// ------- kernel 2: split-bf16 MFMA Gram, upper-tri tiles, mirrored store -------
__global__ __launch_bounds__(256) void dist_kernel(const uint4* __restrict__ fhi,
                                                   const uint4* __restrict__ flo,
                                                   const float* __restrict__ sq,
                                                   float* __restrict__ dist) {
    const int b = blockIdx.x & 7;               // batch = id&7 -> XCD-pinned operand panels
    int tri = blockIdx.x >> 3, rt = 0;          // 0..35 -> upper-tri tile (rt <= ct)
    while (tri >= 8 - rt) { tri -= 8 - rt; ++rt; }
    const int ct = rt + tri;
    const bool diag = (rt == ct);
    const int tid = threadIdx.x;
    const int w = tid >> 6, lane = tid & 63;
    const int R = rt * 128 + (w & 1) * 64;      // wave rows (2 tiles of 32)
    const int C = ct * 128 + (w >> 1) * 64;     // wave cols
    const int h = lane >> 5, fr = lane & 31;

    size_t a0 = ((size_t)b * 64 + h) * 1024 + R + fr;   // uint4 units; +2048 per k16-step
    size_t b0 = ((size_t)b * 64 + h) * 1024 + C + fr;

    f32x16 acc00, acc01, acc10, acc11;
    #pragma unroll
    for (int i = 0; i < 16; ++i) { acc00[i] = 0.f; acc01[i] = 0.f; acc10[i] = 0.f; acc11[i] = 0.f; }

    bf16x8 A0h = *(const bf16x8*)(fhi + a0), A1h = *(const bf16x8*)(fhi + a0 + 32);
    bf16x8 A0l = *(const bf16x8*)(flo + a0), A1l = *(const bf16x8*)(flo + a0 + 32);
    bf16x8 B0h = *(const bf16x8*)(fhi + b0), B1h = *(const bf16x8*)(fhi + b0 + 32);
    bf16x8 B0l = *(const bf16x8*)(flo + b0), B1l = *(const bf16x8*)(flo + b0 + 32);

    #pragma unroll 4
    for (int s = 0; s < 32; ++s) {
        const bf16x8 cA0h = A0h, cA1h = A1h, cA0l = A0l, cA1l = A1l;
        const bf16x8 cB0h = B0h, cB1h = B1h, cB0l = B0l, cB1l = B1l;
        if (s < 31) {
            a0 += 2048; b0 += 2048;
            A0h = *(const bf16x8*)(fhi + a0); A1h = *(const bf16x8*)(fhi + a0 + 32);
            A0l = *(const bf16x8*)(flo + a0); A1l = *(const bf16x8*)(flo + a0 + 32);
            B0h = *(const bf16x8*)(fhi + b0); B1h = *(const bf16x8*)(fhi + b0 + 32);
            B0l = *(const bf16x8*)(flo + b0); B1l = *(const bf16x8*)(flo + b0 + 32);
        }
        acc00 = __builtin_amdgcn_mfma_f32_32x32x16_bf16(cA0h, cB0h, acc00, 0, 0, 0);
        acc01 = __builtin_amdgcn_mfma_f32_32x32x16_bf16(cA0h, cB1h, acc01, 0, 0, 0);
        acc10 = __builtin_amdgcn_mfma_f32_32x32x16_bf16(cA1h, cB0h, acc10, 0, 0, 0);
        acc11 = __builtin_amdgcn_mfma_f32_32x32x16_bf16(cA1h, cB1h, acc11, 0, 0, 0);
        acc00 = __builtin_amdgcn_mfma_f32_32x32x16_bf16(cA0h, cB0l, acc00, 0, 0, 0);
        acc01 = __builtin_amdgcn_mfma_f32_32x32x16_bf16(cA0h, cB1l, acc01, 0, 0, 0);
        acc10 = __builtin_amdgcn_mfma_f32_32x32x16_bf16(cA1h, cB0l, acc10, 0, 0, 0);
        acc11 = __builtin_amdgcn_mfma_f32_32x32x16_bf16(cA1h, cB1l, acc11, 0, 0, 0);
        acc00 = __builtin_amdgcn_mfma_f32_32x32x16_bf16(cA0l, cB0h, acc00, 0, 0, 0);
        acc01 = __builtin_amdgcn_mfma_f32_32x32x16_bf16(cA0l, cB1h, acc01, 0, 0, 0);
        acc10 = __builtin_amdgcn_mfma_f32_32x32x16_bf16(cA1l, cB0h, acc10, 0, 0, 0);
        acc11 = __builtin_amdgcn_mfma_f32_32x32x16_bf16(cA1l, cB1h, acc11, 0, 0, 0);
    }

    // ---- epilogue: two phases through a 64x128 LDS stage; mirrored stores ----
    __shared__ float lds[64 * LP];
    const int bF = b * FF;
    const int R0 = rt * 128, C0 = ct * 128;
    const float sqc0 = sq[bF + C + fr], sqc1 = sq[bF + C + fr + 32];
    const int lcb = (w >> 1) * 64 + fr;         // local col base in 0..127

    #pragma unroll
    for (int p = 0; p < 2; ++p) {
        if ((w & 1) == p) {                     // this wave's rows belong to phase p
            #pragma unroll
            for (int reg = 0; reg < 16; ++reg) {
                const int rp = 4 * h + (reg & 3) + 8 * (reg >> 2);   // 0..31
                const float sqr0 = sq[bF + R + rp];
                const float sqr1 = sq[bF + R + rp + 32];
                lds[rp * LP + lcb] =
                    sqrtf(fmaxf(sqr0 + sqc0 - 2.0f * acc00[reg], 0.f)) * RCP_SQRT_C;
                lds[rp * LP + lcb + 32] =
                    sqrtf(fmaxf(sqr0 + sqc1 - 2.0f * acc01[reg], 0.f)) * RCP_SQRT_C;
                lds[(rp + 32) * LP + lcb] =
                    sqrtf(fmaxf(sqr1 + sqc0 - 2.0f * acc10[reg], 0.f)) * RCP_SQRT_C;
                lds[(rp + 32) * LP + lcb + 32] =
                    sqrtf(fmaxf(sqr1 + sqc1 - 2.0f * acc11[reg], 0.f)) * RCP_SQRT_C;
            }
        }
        __syncthreads();
        if (!diag) {
            for (int q = tid; q < 64 * 128; q += 256) {
                const int lr = q >> 7, c = q & 127;
                dist[((size_t)bF + R0 + p * 64 + lr) * FF + C0 + c] = lds[lr * LP + c];
            }
            for (int q = tid; q < 64 * 128; q += 256) {
                const int lr = q & 63, c = q >> 6;
                dist[((size_t)bF + C0 + c) * FF + R0 + p * 64 + lr] = lds[lr * LP + c];
            }
        } else if (p == 0) {
            for (int q = tid; q < 64 * 128; q += 256) {
                const int i = q >> 7, j = q & 127;
                const float v = (i == j) ? 0.f : (i < j ? lds[i * LP + j] : lds[j * LP + i]);
                dist[((size_t)bF + R0 + i) * FF + C0 + j] = v;
            }
            for (int q = tid; q < 64 * 64; q += 256) {
                const int i = 64 + (q >> 6), j = q & 63;
                dist[((size_t)bF + R0 + i) * FF + C0 + j] = lds[j * LP + i];
            }
        } else {
            for (int q = tid; q < 64 * 64; q += 256) {
                const int i = 64 + (q >> 6), j = 64 + (q & 63);
                const float v = (i == j) ? 0.f
                               : (i < j ? lds[(i - 64) * LP + j] : lds[(j - 64) * LP + i]);
                dist[((size_t)bF + R0 + i) * FF + C0 + j] = v;
            }
        }
        __syncthreads();
    }
}

// ======== kernel 3: fused rowstat + scoremin + topk + gather ========
// Exactly 256 workgroups (<= 1 per CU, co-residency guaranteed) with
// threadfence+atomic grid syncs (rocPRIM decoupled-lookback pattern).
// Exactness: dist[r][r] == 0.0 exactly and all dist >= 0, so the row's two
// smallest are {0, min_{j!=r}} and density = exp(-0.5*min^2) bit-identically.
__global__ __launch_bounds__(256) void stats_kernel(const float* __restrict__ dist,
                                                    const float* __restrict__ noise,
                                                    float* __restrict__ density,
                                                    unsigned* __restrict__ ctrl,  // [0..7] dmx, [8] syncA, [9] syncD, [10..17] batchcnt
                                                    float* __restrict__ score,
                                                    int* __restrict__ selsort,
                                                    const float* __restrict__ x,
                                                    const float* __restrict__ pos,
                                                    float* __restrict__ out) {
    const int t = threadIdx.x, wid = t >> 6, lane = t & 63;
    const int g = blockIdx.x;
    const int b = g >> 5;                        // 32 blocks per batch, rows g*32..g*32+31
    unsigned* dmx = ctrl;
    unsigned* syncA = ctrl + 8;
    unsigned* syncD = ctrl + 9;
    unsigned* bcnt  = ctrl + 10;

    // ---- phase A: density (exp(-0.5*min^2)+noise) + per-block max -> atomicMax ----
    __shared__ float sdens[4][8];                // this block's 32 densities for phase B
    float wmax = -FLT_MAX;
    #pragma unroll
    for (int k = 0; k < 8; ++k) {
        const int r = g * 32 + wid * 8 + k;
        const int dcol = r & 1023;
        const float* dr = dist + (size_t)r * FF + lane * 4;
        float mn = FLT_MAX, mx = -FLT_MAX;
        #pragma unroll
        for (int j = 0; j < 4; ++j) {
            float4 d = *(const float4*)(dr + j * 256);
            mx = fmaxf(mx, fmaxf(fmaxf(d.x, d.y), fmaxf(d.z, d.w)));
            const int c0 = lane * 4 + j * 256;
            d.x = (c0 + 0 == dcol) ? FLT_MAX : d.x;
            d.y = (c0 + 1 == dcol) ? FLT_MAX : d.y;
            d.z = (c0 + 2 == dcol) ? FLT_MAX : d.z;
            d.w = (c0 + 3 == dcol) ? FLT_MAX : d.w;
            mn = fminf(mn, fminf(fminf(d.x, d.y), fminf(d.z, d.w)));
        }
        #pragma unroll
        for (int off = 32; off > 0; off >>= 1) {
            mn = fminf(mn, __shfl_down(mn, off));
            mx = fmaxf(mx, __shfl_down(mx, off));
        }
        if (lane == 0) {
            const float dv = expf(-0.5f * mn * mn) + noise[r] * 1e-6f;
            density[r] = dv;
            sdens[wid][k] = dv;
            wmax = fmaxf(wmax, mx);
        }
    }
    __shared__ float swm[4];
    if (lane == 0) swm[wid] = wmax;
    __syncthreads();
    // ---- grid sync A (all densities + dmx visible) ----
    if (t == 0) {
        atomicMax(&dmx[b], __float_as_uint(fmaxf(fmaxf(swm[0], swm[1]), fmaxf(swm[2], swm[3]))));
        __threadfence();
        atomicAdd(syncA, 1u);
        while (__hip_atomic_load(syncA, __ATOMIC_ACQUIRE, __HIP_MEMORY_SCOPE_AGENT) < 256u)
            __builtin_amdgcn_s_sleep(8);
    }
    __syncthreads();
    __threadfence();

    // ---- phase B: masked min -> score (density of whole batch preloaded per lane) ----
    const float dmaxb = __uint_as_float(
        __hip_atomic_load(&dmx[b], __ATOMIC_RELAXED, __HIP_MEMORY_SCOPE_AGENT));
    float e[16];
    {
        const volatile float* db = density + (size_t)b * FF;
        #pragma unroll
        for (int j = 0; j < 16; ++j) e[j] = db[lane + j * 64];
    }
    #pragma unroll
    for (int k = 0; k < 8; ++k) {
        const int r = g * 32 + wid * 8 + k;
        const float dme = sdens[wid][k];         // own block's density (computed locally)
        const float* dr = dist + (size_t)r * FF;
        float mn = FLT_MAX;
        #pragma unroll
        for (int j = 0; j < 16; ++j) {
            const float d = dr[lane + j * 64];
            mn = fminf(mn, (e[j] > dme) ? d : FLT_MAX);
        }
        #pragma unroll
        for (int off = 32; off > 0; off >>= 1) mn = fminf(mn, __shfl_down(mn, off));
        if (lane == 0) score[r] = ((mn == FLT_MAX) ? dmaxb : mn) * dme;
    }
    __syncthreads();

    // ---- per-batch completion; last of the 32 blocks runs the radix top-81 ----
    __shared__ int slast;
    if (t == 0) {
        __threadfence();
        slast = (atomicAdd(&bcnt[b], 1u) == 31u) ? 1 : 0;
    }
    __syncthreads();
    if (slast) {
        __threadfence();                         // acquire: other blocks' scores
        const volatile float* sb = score + (size_t)b * FF;
        unsigned v[4];
        #pragma unroll
        for (int j = 0; j < 4; ++j) v[j] = __float_as_uint(sb[t + 256 * j]);

        __shared__ unsigned hist[256];
        __shared__ unsigned wtot[4];
        __shared__ unsigned sh_byte, sh_kk;
        unsigned prefix = 0, kk = TOK;
        #pragma unroll
        for (int pass = 0; pass < 4; ++pass) {
            const int sh = 24 - 8 * pass;
            const unsigned pmask = (pass == 0) ? 0u : (0xFFFFFFFFu << (sh + 8));
            hist[t] = 0;
            __syncthreads();
            #pragma unroll
            for (int j = 0; j < 4; ++j)
                if ((v[j] & pmask) == prefix) atomicAdd(&hist[(v[j] >> sh) & 255], 1u);
            __syncthreads();
            const unsigned cnt = hist[t];
            unsigned s = cnt;
            #pragma unroll
            for (int off = 1; off < 64; off <<= 1) {
                const unsigned o = __shfl_down(s, off);
                if (lane + off < 64) s += o;
            }
            if (lane == 0) wtot[wid] = s;
            __syncthreads();
            unsigned hi2 = 0;
            for (int w2 = wid + 1; w2 < 4; ++w2) hi2 += wtot[w2];
            const unsigned S_incl = s + hi2;
            const unsigned S_excl = S_incl - cnt;
            if (S_excl < kk && kk <= S_incl) { sh_byte = (unsigned)t; sh_kk = kk - S_excl; }
            __syncthreads();
            prefix |= (sh_byte << sh);
            kk = sh_kk;
        }
        const unsigned T = prefix;

        __shared__ unsigned cgt[16], ceq[16];
        unsigned long long bgt[4], beq[4];
        #pragma unroll
        for (int j = 0; j < 4; ++j) {
            bgt[j] = __ballot(v[j] > T);
            beq[j] = __ballot(v[j] == T);
            if (lane == 0) {
                cgt[j * 4 + wid] = (unsigned)__popcll(bgt[j]);
                ceq[j * 4 + wid] = (unsigned)__popcll(beq[j]);
            }
        }
        __syncthreads();
        const unsigned long long below = (1ULL << lane) - 1ULL;
        #pragma unroll
        for (int j = 0; j < 4; ++j) {
            const bool gt = v[j] > T, eq = v[j] == T;
            if (!gt && !eq) continue;
            const int c = j * 4 + wid;
            unsigned bq_gt = 0, bq_eq = 0;
            for (int cc = 0; cc < c; ++cc) { bq_gt += cgt[cc]; bq_eq += ceq[cc]; }
            const unsigned wgt = (unsigned)__popcll(bgt[j] & below);
            const unsigned weq = (unsigned)__popcll(beq[j] & below);
            unsigned pos_;
            if (gt) {
                const unsigned eq_before = bq_eq + weq;
                pos_ = bq_gt + wgt + ((eq_before < kk) ? eq_before : kk);
            } else {
                const unsigned eord = bq_eq + weq;
                if (eord >= kk) continue;
                pos_ = bq_gt + wgt + eord;
            }
            selsort[b * TOK + pos_] = (int)(t + 256 * j);
        }
        __threadfence();                         // release selsort before counting in
    }
    __syncthreads();
    if (t == 0) atomicAdd(syncD, 1u);            // last blocks add after topk -> gate

    // ---- grid sync D (all selsort written) ----
    if (t == 0) {
        while (__hip_atomic_load(syncD, __ATOMIC_ACQUIRE, __HIP_MEMORY_SCOPE_AGENT) < 256u)
            __builtin_amdgcn_s_sleep(8);
    }
    __syncthreads();
    __threadfence();

    // ---- phase D: gather + pos-embed, grid-strided over 256 blocks ----
    __shared__ int ssel[BB * TOK];
    for (int q = t; q < BB * TOK; q += 256) ssel[q] = *((volatile const int*)selsort + q);
    __syncthreads();
    const size_t total = (size_t)BB * TOK * NJ * (CH / 4);
    for (size_t i = (size_t)g * 256 + t; i < total; i += 256 * 256) {
        const int c4 = (int)(i & (CH / 4 - 1));
        size_t r = i >> 7;
        const int n = (int)(r % NJ); r /= NJ;
        const int tok = (int)(r % TOK);
        const int bb = (int)(r / TOK);
        const int f = ssel[bb * TOK + tok];
        float4 v = *(const float4*)(x + (((size_t)(bb * FF + f)) * NJ + n) * CH + c4 * 4);
        const float4 p = *(const float4*)(pos + (size_t)tok * CH + c4 * 4);
        v.x += p.x; v.y += p.y; v.z += p.z; v.w += p.w;
        *(float4*)(out + i * 4) = v;
    }
}

extern "C" void kernel_launch(void* const* d_in, const int* in_sizes, int n_in,
                              void* d_out, int out_size, void* d_ws, size_t ws_size,
                              hipStream_t stream) {
    const float* x     = (const float*)d_in[0];
    const float* pos   = (const float*)d_in[1];
    const float* noise = (const float*)d_in[2];
    float* out = (float*)d_out;

    uint4* fhi    = (uint4*)d_ws;                           // 8.4 MB
    uint4* flo    = fhi + (size_t)BB * 32 * 2 * 1024;       // 8.4 MB
    float* dist   = (float*)(flo + (size_t)BB * 32 * 2 * 1024);  // 33.5 MB
    float* sq      = dist + (size_t)BB * FF * FF;
    float* density = sq + BB * FF;
    unsigned* ctrl = (unsigned*)(density + BB * FF);        // dmx[8] + sync[2] + bcnt[8]
    float* score   = (float*)(ctrl + 24);
    int*   selsort = (int*)(score + BB * FF);

    pool_kernel<<<(BB * FF) / 4, 256, 0, stream>>>(x, fhi, flo, sq, ctrl);
    dist_kernel<<<288, 256, 0, stream>>>(fhi, flo, sq, dist);   // flat grid, batch = id&7
    stats_kernel<<<256, 256, 0, stream>>>(dist, noise, density, ctrl, score, selsort,
                                          x, pos, out);
}